// Round 1
// baseline (202.941 us; speedup 1.0000x reference)
//
#include <hip/hip_runtime.h>
#include <stdint.h>
#include <stddef.h>

#define B_ROWS 8192
#define NX 2048
#define NH 512
#define NY 1024

typedef __attribute__((ext_vector_type(8))) short bf16x8;
typedef __attribute__((ext_vector_type(4))) short bf16x4;
typedef __attribute__((ext_vector_type(4))) float f32x4;

static __device__ __forceinline__ unsigned short f2bf(float f) {
    union { float f; unsigned int u; } c; c.f = f;
    unsigned int r = 0x7FFFu + ((c.u >> 16) & 1u);
    return (unsigned short)((c.u + r) >> 16);
}
static __device__ __forceinline__ float bf2f(unsigned short b) {
    union { unsigned int u; float f; } c; c.u = ((unsigned int)b) << 16;
    return c.f;
}

static __device__ __forceinline__ void glld16(const void* g, void* l) {
    __builtin_amdgcn_global_load_lds(
        (const __attribute__((address_space(1))) unsigned int*)g,
        (__attribute__((address_space(3))) unsigned int*)l, 16, 0, 0);
}

// ---------------- weight prep ----------------

// W_fc [NH, NX] fp32 -> bf16
__global__ __launch_bounds__(256) void cast_wfc_kernel(const float* __restrict__ w,
                                                       unsigned short* __restrict__ wb) {
    int idx = (blockIdx.x * 256 + threadIdx.x) * 4;  // grid sized to cover exactly
    float4 v = *(const float4*)&w[idx];
    bf16x4 o;
    o[0] = (short)f2bf(v.x); o[1] = (short)f2bf(v.y);
    o[2] = (short)f2bf(v.z); o[3] = (short)f2bf(v.w);
    *(bf16x4*)&wb[idx] = o;
}

// W_q [NY, NH] fp32 -> bf16 + row sumsq. One wave per row.
__global__ __launch_bounds__(256) void prep_wq_kernel(const float* __restrict__ wq,
                                                      unsigned short* __restrict__ wqb,
                                                      float* __restrict__ wqsq) {
    int lane = threadIdx.x & 63;
    int row = blockIdx.x * 4 + (threadIdx.x >> 6);
    const float* p = wq + (size_t)row * NH + lane * 8;
    float4 a = *(const float4*)p;
    float4 b = *(const float4*)(p + 4);
    bf16x8 o;
    o[0] = (short)f2bf(a.x); o[1] = (short)f2bf(a.y);
    o[2] = (short)f2bf(a.z); o[3] = (short)f2bf(a.w);
    o[4] = (short)f2bf(b.x); o[5] = (short)f2bf(b.y);
    o[6] = (short)f2bf(b.z); o[7] = (short)f2bf(b.w);
    *(bf16x8*)&wqb[(size_t)row * NH + lane * 8] = o;
    float s = a.x*a.x + a.y*a.y + a.z*a.z + a.w*a.w
            + b.x*b.x + b.y*b.y + b.z*b.z + b.w*b.w;
    #pragma unroll
    for (int off = 32; off > 0; off >>= 1) s += __shfl_xor(s, off);
    if (lane == 0) wqsq[row] = s;
}

// ---------------- GEMM1: h = relu(relu(x) @ W_fc^T + b) -> bf16 ----------------
// tile 64(M) x 128(N), BK=32, 4 waves (2x2), wave tile 32x64, acc 2x4
__global__ __launch_bounds__(256, 2) void gemm1_kernel(const float* __restrict__ x,
                                                       const unsigned short* __restrict__ wfcb,
                                                       const float* __restrict__ b_fc,
                                                       unsigned short* __restrict__ hb) {
    __shared__ unsigned short As[64 * 32];   // row-major [64][32] bf16
    __shared__ unsigned short Bs[128 * 32];  // row-major [128][32] bf16

    const int tid = threadIdx.x;
    const int lane = tid & 63;
    const int wave = tid >> 6;
    const int wm = wave >> 1, wn = wave & 1;
    const int quad = lane >> 4;
    const int m0 = blockIdx.y * 64;
    const int n0 = blockIdx.x * 128;

    f32x4 acc[2][4];
    #pragma unroll
    for (int i = 0; i < 2; ++i)
        #pragma unroll
        for (int j = 0; j < 4; ++j) acc[i][j] = (f32x4)(0.0f);

    // A staging: thread loads rows ar, ar+32; 4 floats at col ac
    const int ar = tid >> 3;
    const int ac = (tid & 7) * 4;
    const float* xg0 = x + (size_t)(m0 + ar) * NX + ac;
    const float* xg1 = x + (size_t)(m0 + ar + 32) * NX + ac;
    unsigned short* asw0 = &As[ar * 32 + ac];
    unsigned short* asw1 = &As[(ar + 32) * 32 + ac];

    // B staging (global_load_lds): wave-uniform LDS base + lane*16
    const int boff0 = wave * 2048 + lane * 16;
    const int boff1 = boff0 + 1024;
    const char* wfcb_bytes = (const char*)wfcb;
    char* BsB = (char*)Bs;

    const unsigned short* ard = &As[(wm * 32 + (lane & 15)) * 32 + quad * 8];
    const unsigned short* brd = &Bs[(wn * 64 + (lane & 15)) * 32 + quad * 8];

    for (int k0 = 0; k0 < NX; k0 += 32) {
        float4 a0 = *(const float4*)(xg0 + k0);
        float4 a1 = *(const float4*)(xg1 + k0);
        __syncthreads();  // prev iter consumers done before LDS overwrite
        glld16(wfcb_bytes + (size_t)(n0 + (boff0 >> 6)) * (NX * 2) + k0 * 2 + (boff0 & 63),
               BsB + wave * 2048);
        glld16(wfcb_bytes + (size_t)(n0 + (boff1 >> 6)) * (NX * 2) + k0 * 2 + (boff1 & 63),
               BsB + wave * 2048 + 1024);
        bf16x4 w0, w1;
        w0[0] = (short)f2bf(fmaxf(a0.x, 0.f)); w0[1] = (short)f2bf(fmaxf(a0.y, 0.f));
        w0[2] = (short)f2bf(fmaxf(a0.z, 0.f)); w0[3] = (short)f2bf(fmaxf(a0.w, 0.f));
        w1[0] = (short)f2bf(fmaxf(a1.x, 0.f)); w1[1] = (short)f2bf(fmaxf(a1.y, 0.f));
        w1[2] = (short)f2bf(fmaxf(a1.z, 0.f)); w1[3] = (short)f2bf(fmaxf(a1.w, 0.f));
        *(bf16x4*)asw0 = w0;
        *(bf16x4*)asw1 = w1;
        __syncthreads();  // staging visible (drains vmcnt for glld too)

        bf16x8 af[2], bfv[4];
        af[0] = *(const bf16x8*)ard;
        af[1] = *(const bf16x8*)(ard + 16 * 32);
        #pragma unroll
        for (int j = 0; j < 4; ++j) bfv[j] = *(const bf16x8*)(brd + j * 16 * 32);
        #pragma unroll
        for (int i = 0; i < 2; ++i)
            #pragma unroll
            for (int j = 0; j < 4; ++j)
                acc[i][j] = __builtin_amdgcn_mfma_f32_16x16x32_bf16(af[i], bfv[j], acc[i][j], 0, 0, 0);
    }

    #pragma unroll
    for (int i = 0; i < 2; ++i) {
        #pragma unroll
        for (int j = 0; j < 4; ++j) {
            int col = n0 + wn * 64 + j * 16 + (lane & 15);
            float bias = b_fc[col];
            #pragma unroll
            for (int r = 0; r < 4; ++r) {
                int row = m0 + wm * 32 + i * 16 + quad * 4 + r;
                float v = fmaxf(acc[i][j][r] + bias, 0.0f);
                hb[(size_t)row * NH + col] = f2bf(v);
            }
        }
    }
}

// ---------------- hsq: per-row ||h||^2 ----------------
__global__ __launch_bounds__(256) void hsq_kernel(const unsigned short* __restrict__ hb,
                                                  float* __restrict__ hsq) {
    int lane = threadIdx.x & 63;
    int row = blockIdx.x * 4 + (threadIdx.x >> 6);
    bf16x8 v = *(const bf16x8*)&hb[(size_t)row * NH + lane * 8];
    float s = 0.f;
    #pragma unroll
    for (int i = 0; i < 8; ++i) {
        float f = bf2f((unsigned short)v[i]);
        s += f * f;
    }
    #pragma unroll
    for (int off = 32; off > 0; off >>= 1) s += __shfl_xor(s, off);
    if (lane == 0) hsq[row] = s;
}

// ---------------- GEMM2 + distance + t ----------------
// tile 128x128, BK=32, 4 waves (2x2), wave tile 64x64, acc 4x4
__global__ __launch_bounds__(256, 2) void gemm2_kernel(const unsigned short* __restrict__ hb,
                                                       const unsigned short* __restrict__ wqb,
                                                       const float* __restrict__ hsq,
                                                       const float* __restrict__ wqsq,
                                                       float* __restrict__ out) {
    __shared__ unsigned short As[128 * 32];
    __shared__ unsigned short Bs[128 * 32];

    const int tid = threadIdx.x;
    const int lane = tid & 63;
    const int wave = tid >> 6;
    const int wm = wave >> 1, wn = wave & 1;
    const int quad = lane >> 4;
    const int m0 = blockIdx.y * 128;
    const int n0 = blockIdx.x * 128;

    f32x4 acc[4][4];
    #pragma unroll
    for (int i = 0; i < 4; ++i)
        #pragma unroll
        for (int j = 0; j < 4; ++j) acc[i][j] = (f32x4)(0.0f);

    const int off0 = wave * 2048 + lane * 16;
    const int off1 = off0 + 1024;
    const char* hbB = (const char*)hb;
    const char* wqB = (const char*)wqb;
    char* AsB = (char*)As;
    char* BsB = (char*)Bs;

    const unsigned short* ard = &As[(wm * 64 + (lane & 15)) * 32 + quad * 8];
    const unsigned short* brd = &Bs[(wn * 64 + (lane & 15)) * 32 + quad * 8];

    for (int k0 = 0; k0 < NH; k0 += 32) {
        __syncthreads();
        glld16(hbB + (size_t)(m0 + (off0 >> 6)) * (NH * 2) + k0 * 2 + (off0 & 63), AsB + wave * 2048);
        glld16(hbB + (size_t)(m0 + (off1 >> 6)) * (NH * 2) + k0 * 2 + (off1 & 63), AsB + wave * 2048 + 1024);
        glld16(wqB + (size_t)(n0 + (off0 >> 6)) * (NH * 2) + k0 * 2 + (off0 & 63), BsB + wave * 2048);
        glld16(wqB + (size_t)(n0 + (off1 >> 6)) * (NH * 2) + k0 * 2 + (off1 & 63), BsB + wave * 2048 + 1024);
        __syncthreads();

        bf16x8 af[4], bfv[4];
        #pragma unroll
        for (int i = 0; i < 4; ++i) af[i] = *(const bf16x8*)(ard + i * 16 * 32);
        #pragma unroll
        for (int j = 0; j < 4; ++j) bfv[j] = *(const bf16x8*)(brd + j * 16 * 32);
        #pragma unroll
        for (int i = 0; i < 4; ++i)
            #pragma unroll
            for (int j = 0; j < 4; ++j)
                acc[i][j] = __builtin_amdgcn_mfma_f32_16x16x32_bf16(af[i], bfv[j], acc[i][j], 0, 0, 0);
    }

    float hs[4][4];
    #pragma unroll
    for (int i = 0; i < 4; ++i)
        #pragma unroll
        for (int r = 0; r < 4; ++r)
            hs[i][r] = hsq[m0 + wm * 64 + i * 16 + quad * 4 + r];

    #pragma unroll
    for (int i = 0; i < 4; ++i) {
        #pragma unroll
        for (int j = 0; j < 4; ++j) {
            int col = n0 + wn * 64 + j * 16 + (lane & 15);
            float wq = wqsq[col];
            #pragma unroll
            for (int r = 0; r < 4; ++r) {
                int row = m0 + wm * 64 + i * 16 + quad * 4 + r;
                float d = hs[i][r] - 2.0f * acc[i][j][r] + wq;
                d = fmaxf(d, 0.0f);
                out[(size_t)row * NY + col] = -__logf(1.0f + d);
            }
        }
    }
}

// ---------------- per-row logsumexp, in place on out ----------------
__global__ __launch_bounds__(256) void lse_kernel(float* __restrict__ out) {
    __shared__ float redm[4];
    __shared__ float reds[4];
    const int tid = threadIdx.x;
    const int lane = tid & 63;
    const int wave = tid >> 6;
    float* p = out + (size_t)blockIdx.x * NY;
    float4 v = ((const float4*)p)[tid];
    float m = fmaxf(fmaxf(v.x, v.y), fmaxf(v.z, v.w));
    #pragma unroll
    for (int off = 32; off > 0; off >>= 1) m = fmaxf(m, __shfl_xor(m, off));
    if (lane == 0) redm[wave] = m;
    __syncthreads();
    m = fmaxf(fmaxf(redm[0], redm[1]), fmaxf(redm[2], redm[3]));
    float s = __expf(v.x - m) + __expf(v.y - m) + __expf(v.z - m) + __expf(v.w - m);
    #pragma unroll
    for (int off = 32; off > 0; off >>= 1) s += __shfl_xor(s, off);
    if (lane == 0) reds[wave] = s;
    __syncthreads();
    s = reds[0] + reds[1] + reds[2] + reds[3];
    float lse = m + __logf(s);
    v.x -= lse; v.y -= lse; v.z -= lse; v.w -= lse;
    ((float4*)p)[tid] = v;
}

extern "C" void kernel_launch(void* const* d_in, const int* in_sizes, int n_in,
                              void* d_out, int out_size, void* d_ws, size_t ws_size,
                              hipStream_t stream) {
    const float* x    = (const float*)d_in[0];
    const float* W_fc = (const float*)d_in[1];
    const float* b_fc = (const float*)d_in[2];
    const float* W_q  = (const float*)d_in[3];
    float* out = (float*)d_out;

    char* ws = (char*)d_ws;
    unsigned short* wfcb = (unsigned short*)(ws);                       // 2 MiB
    unsigned short* wqb  = (unsigned short*)(ws + 2097152);             // 1 MiB
    float*          wqsq = (float*)(ws + 3145728);                      // 4 KiB
    unsigned short* hb   = (unsigned short*)(ws + 3149824);             // 8 MiB
    float*          hsq  = (float*)(ws + 11538432);                     // 32 KiB

    cast_wfc_kernel<<<(NH * NX) / (256 * 4), 256, 0, stream>>>(W_fc, wfcb);
    prep_wq_kernel<<<NY / 4, 256, 0, stream>>>(W_q, wqb, wqsq);
    gemm1_kernel<<<dim3(NH / 128, B_ROWS / 64), 256, 0, stream>>>(x, wfcb, b_fc, hb);
    hsq_kernel<<<B_ROWS / 4, 256, 0, stream>>>(hb, hsq);
    gemm2_kernel<<<dim3(NY / 128, B_ROWS / 128), 256, 0, stream>>>(hb, wqb, hsq, wqsq, out);
    lse_kernel<<<B_ROWS, 256, 0, stream>>>(out);
}

// Round 2
// 182.989 us; speedup vs baseline: 1.1090x; 1.1090x over previous
//
#include <hip/hip_runtime.h>
#include <stdint.h>
#include <stddef.h>

#define B_ROWS 8192
#define NX 2048
#define NH 512
#define NY 1024

typedef __attribute__((ext_vector_type(8))) short bf16x8;
typedef __attribute__((ext_vector_type(4))) short bf16x4;
typedef __attribute__((ext_vector_type(4))) float f32x4;

static __device__ __forceinline__ unsigned short f2bf(float f) {
    union { float f; unsigned int u; } c; c.f = f;
    unsigned int r = 0x7FFFu + ((c.u >> 16) & 1u);
    return (unsigned short)((c.u + r) >> 16);
}
static __device__ __forceinline__ float bf2f(unsigned short b) {
    union { unsigned int u; float f; } c; c.u = ((unsigned int)b) << 16;
    return c.f;
}

static __device__ __forceinline__ void glld16(const void* g, void* l) {
    __builtin_amdgcn_global_load_lds(
        (const __attribute__((address_space(1))) unsigned int*)g,
        (__attribute__((address_space(3))) unsigned int*)l, 16, 0, 0);
}

// ---------------- prep kernels ----------------

// relu(x) -> bf16, [B_ROWS, NX]
__global__ __launch_bounds__(256) void cast_x_kernel(const float* __restrict__ x,
                                                     unsigned short* __restrict__ xb) {
    size_t idx = (size_t)(blockIdx.x * 256 + threadIdx.x) * 8;
    float4 a = *(const float4*)&x[idx];
    float4 b = *(const float4*)&x[idx + 4];
    bf16x8 o;
    o[0] = (short)f2bf(fmaxf(a.x, 0.f)); o[1] = (short)f2bf(fmaxf(a.y, 0.f));
    o[2] = (short)f2bf(fmaxf(a.z, 0.f)); o[3] = (short)f2bf(fmaxf(a.w, 0.f));
    o[4] = (short)f2bf(fmaxf(b.x, 0.f)); o[5] = (short)f2bf(fmaxf(b.y, 0.f));
    o[6] = (short)f2bf(fmaxf(b.z, 0.f)); o[7] = (short)f2bf(fmaxf(b.w, 0.f));
    *(bf16x8*)&xb[idx] = o;
}

// W_fc [NH, NX] fp32 -> bf16
__global__ __launch_bounds__(256) void cast_wfc_kernel(const float* __restrict__ w,
                                                       unsigned short* __restrict__ wb) {
    int idx = (blockIdx.x * 256 + threadIdx.x) * 4;
    float4 v = *(const float4*)&w[idx];
    bf16x4 o;
    o[0] = (short)f2bf(v.x); o[1] = (short)f2bf(v.y);
    o[2] = (short)f2bf(v.z); o[3] = (short)f2bf(v.w);
    *(bf16x4*)&wb[idx] = o;
}

// W_q [NY, NH] fp32 -> bf16 + row sumsq. One wave per row.
__global__ __launch_bounds__(256) void prep_wq_kernel(const float* __restrict__ wq,
                                                      unsigned short* __restrict__ wqb,
                                                      float* __restrict__ wqsq) {
    int lane = threadIdx.x & 63;
    int row = blockIdx.x * 4 + (threadIdx.x >> 6);
    const float* p = wq + (size_t)row * NH + lane * 8;
    float4 a = *(const float4*)p;
    float4 b = *(const float4*)(p + 4);
    bf16x8 o;
    o[0] = (short)f2bf(a.x); o[1] = (short)f2bf(a.y);
    o[2] = (short)f2bf(a.z); o[3] = (short)f2bf(a.w);
    o[4] = (short)f2bf(b.x); o[5] = (short)f2bf(b.y);
    o[6] = (short)f2bf(b.z); o[7] = (short)f2bf(b.w);
    *(bf16x8*)&wqb[(size_t)row * NH + lane * 8] = o;
    float s = a.x*a.x + a.y*a.y + a.z*a.z + a.w*a.w
            + b.x*b.x + b.y*b.y + b.z*b.z + b.w*b.w;
    #pragma unroll
    for (int off = 32; off > 0; off >>= 1) s += __shfl_xor(s, off);
    if (lane == 0) wqsq[row] = s;
}

// ---------------- GEMM1: h = relu(xb @ wfcb^T + b) -> bf16 ----------------
// tile 64(M) x 128(N), BK=64, 4 waves 2x2, wave tile 32x64, acc 2x4.
// Both operands staged with global_load_lds(16B); global fetch XOR-swizzled
// (gchunk = (lane&7)^(lane>>3)) so LDS rows of 128B read conflict-free.
__global__ __launch_bounds__(256, 2) void gemm1_kernel(const unsigned short* __restrict__ xb,
                                                       const unsigned short* __restrict__ wfcb,
                                                       const float* __restrict__ b_fc,
                                                       unsigned short* __restrict__ hb) {
    __shared__ unsigned short As[64 * 64];    // [64 rows][64 k] bf16, 8 KiB
    __shared__ unsigned short Bs[128 * 64];   // [128 rows][64 k] bf16, 16 KiB

    const int tid = threadIdx.x;
    const int lane = tid & 63;
    const int wave = tid >> 6;
    const int wm = wave >> 1, wn = wave & 1;
    const int quad = lane >> 4;
    const int r = lane & 15;
    const int m0 = blockIdx.y * 64;
    const int n0 = blockIdx.x * 128;

    f32x4 acc[2][4];
    #pragma unroll
    for (int i = 0; i < 2; ++i)
        #pragma unroll
        for (int j = 0; j < 4; ++j) acc[i][j] = (f32x4)(0.0f);

    // staging: per glld chunk = 8 rows x 128 bytes; lane covers
    // row R0+(lane>>3), global col chunk (lane&7)^(lane>>3)
    const int lrow = lane >> 3;
    const int gch = (lane & 7) ^ lrow;
    const char* xbB = (const char*)xb;
    const char* wfB = (const char*)wfcb;
    char* AsB = (char*)As;
    char* BsB = (char*)Bs;

    // fragment read offsets (bytes): row*128 + ((s*4+quad)^ (row&7))*16
    const int xk = r & 7;
    const int ch0 = ((quad) ^ xk) * 16;
    const int ch1 = ((4 + quad) ^ xk) * 16;
    const char* ardp = AsB + (wm * 32 + r) * 128;
    const char* brdp = BsB + (wn * 64 + r) * 128;

    for (int k0 = 0; k0 < NX; k0 += 64) {
        __syncthreads();
        // A: 64 rows -> 8 chunks, 2 per wave
        #pragma unroll
        for (int c = 0; c < 2; ++c) {
            int R0 = wave * 16 + c * 8;
            glld16(xbB + (size_t)(m0 + R0 + lrow) * (NX * 2) + k0 * 2 + gch * 16,
                   AsB + R0 * 128);
        }
        // B: 128 rows -> 16 chunks, 4 per wave
        #pragma unroll
        for (int c = 0; c < 4; ++c) {
            int R0 = wave * 32 + c * 8;
            glld16(wfB + (size_t)(n0 + R0 + lrow) * (NX * 2) + k0 * 2 + gch * 16,
                   BsB + R0 * 128);
        }
        __syncthreads();

        #pragma unroll
        for (int s = 0; s < 2; ++s) {
            const int ch = s ? ch1 : ch0;
            bf16x8 af[2], bfv[4];
            #pragma unroll
            for (int i = 0; i < 2; ++i) af[i] = *(const bf16x8*)(ardp + i * 16 * 128 + ch);
            #pragma unroll
            for (int j = 0; j < 4; ++j) bfv[j] = *(const bf16x8*)(brdp + j * 16 * 128 + ch);
            #pragma unroll
            for (int i = 0; i < 2; ++i)
                #pragma unroll
                for (int j = 0; j < 4; ++j)
                    acc[i][j] = __builtin_amdgcn_mfma_f32_16x16x32_bf16(af[i], bfv[j], acc[i][j], 0, 0, 0);
        }
    }

    #pragma unroll
    for (int i = 0; i < 2; ++i) {
        #pragma unroll
        for (int j = 0; j < 4; ++j) {
            int col = n0 + wn * 64 + j * 16 + r;
            float bias = b_fc[col];
            #pragma unroll
            for (int rr = 0; rr < 4; ++rr) {
                int row = m0 + wm * 32 + i * 16 + quad * 4 + rr;
                float v = fmaxf(acc[i][j][rr] + bias, 0.0f);
                hb[(size_t)row * NH + col] = f2bf(v);
            }
        }
    }
}

// ---------------- hsq: per-row ||h||^2 ----------------
__global__ __launch_bounds__(256) void hsq_kernel(const unsigned short* __restrict__ hb,
                                                  float* __restrict__ hsq) {
    int lane = threadIdx.x & 63;
    int row = blockIdx.x * 4 + (threadIdx.x >> 6);
    bf16x8 v = *(const bf16x8*)&hb[(size_t)row * NH + lane * 8];
    float s = 0.f;
    #pragma unroll
    for (int i = 0; i < 8; ++i) {
        float f = bf2f((unsigned short)v[i]);
        s += f * f;
    }
    #pragma unroll
    for (int off = 32; off > 0; off >>= 1) s += __shfl_xor(s, off);
    if (lane == 0) hsq[row] = s;
}

// ---------------- GEMM2 + distance + t ----------------
// tile 128x128, BK=64, 4 waves 2x2, wave tile 64x64, acc 4x4. Same swizzle.
__global__ __launch_bounds__(256, 2) void gemm2_kernel(const unsigned short* __restrict__ hb,
                                                       const unsigned short* __restrict__ wqb,
                                                       const float* __restrict__ hsq,
                                                       const float* __restrict__ wqsq,
                                                       float* __restrict__ out) {
    __shared__ unsigned short As[128 * 64];   // 16 KiB
    __shared__ unsigned short Bs[128 * 64];   // 16 KiB

    const int tid = threadIdx.x;
    const int lane = tid & 63;
    const int wave = tid >> 6;
    const int wm = wave >> 1, wn = wave & 1;
    const int quad = lane >> 4;
    const int r = lane & 15;
    const int m0 = blockIdx.y * 128;
    const int n0 = blockIdx.x * 128;

    f32x4 acc[4][4];
    #pragma unroll
    for (int i = 0; i < 4; ++i)
        #pragma unroll
        for (int j = 0; j < 4; ++j) acc[i][j] = (f32x4)(0.0f);

    const int lrow = lane >> 3;
    const int gch = (lane & 7) ^ lrow;
    const char* hbB = (const char*)hb;
    const char* wqB = (const char*)wqb;
    char* AsB = (char*)As;
    char* BsB = (char*)Bs;

    const int xk = r & 7;
    const int ch0 = ((quad) ^ xk) * 16;
    const int ch1 = ((4 + quad) ^ xk) * 16;
    const char* ardp = AsB + (wm * 64 + r) * 128;
    const char* brdp = BsB + (wn * 64 + r) * 128;

    for (int k0 = 0; k0 < NH; k0 += 64) {
        __syncthreads();
        #pragma unroll
        for (int c = 0; c < 4; ++c) {
            int R0 = wave * 32 + c * 8;
            glld16(hbB + (size_t)(m0 + R0 + lrow) * (NH * 2) + k0 * 2 + gch * 16,
                   AsB + R0 * 128);
            glld16(wqB + (size_t)(n0 + R0 + lrow) * (NH * 2) + k0 * 2 + gch * 16,
                   BsB + R0 * 128);
        }
        __syncthreads();

        #pragma unroll
        for (int s = 0; s < 2; ++s) {
            const int ch = s ? ch1 : ch0;
            bf16x8 af[4], bfv[4];
            #pragma unroll
            for (int i = 0; i < 4; ++i) af[i] = *(const bf16x8*)(ardp + i * 16 * 128 + ch);
            #pragma unroll
            for (int j = 0; j < 4; ++j) bfv[j] = *(const bf16x8*)(brdp + j * 16 * 128 + ch);
            #pragma unroll
            for (int i = 0; i < 4; ++i)
                #pragma unroll
                for (int j = 0; j < 4; ++j)
                    acc[i][j] = __builtin_amdgcn_mfma_f32_16x16x32_bf16(af[i], bfv[j], acc[i][j], 0, 0, 0);
        }
    }

    float hs[4][4];
    #pragma unroll
    for (int i = 0; i < 4; ++i)
        #pragma unroll
        for (int rr = 0; rr < 4; ++rr)
            hs[i][rr] = hsq[m0 + wm * 64 + i * 16 + quad * 4 + rr];

    #pragma unroll
    for (int i = 0; i < 4; ++i) {
        #pragma unroll
        for (int j = 0; j < 4; ++j) {
            int col = n0 + wn * 64 + j * 16 + r;
            float wq = wqsq[col];
            #pragma unroll
            for (int rr = 0; rr < 4; ++rr) {
                int row = m0 + wm * 64 + i * 16 + quad * 4 + rr;
                float d = hs[i][rr] - 2.0f * acc[i][j][rr] + wq;
                d = fmaxf(d, 0.0f);
                out[(size_t)row * NY + col] = -__logf(1.0f + d);
            }
        }
    }
}

// ---------------- per-row logsumexp, in place on out ----------------
__global__ __launch_bounds__(256) void lse_kernel(float* __restrict__ out) {
    __shared__ float redm[4];
    __shared__ float reds[4];
    const int tid = threadIdx.x;
    const int lane = tid & 63;
    const int wave = tid >> 6;
    float* p = out + (size_t)blockIdx.x * NY;
    float4 v = ((const float4*)p)[tid];
    float m = fmaxf(fmaxf(v.x, v.y), fmaxf(v.z, v.w));
    #pragma unroll
    for (int off = 32; off > 0; off >>= 1) m = fmaxf(m, __shfl_xor(m, off));
    if (lane == 0) redm[wave] = m;
    __syncthreads();
    m = fmaxf(fmaxf(redm[0], redm[1]), fmaxf(redm[2], redm[3]));
    float s = __expf(v.x - m) + __expf(v.y - m) + __expf(v.z - m) + __expf(v.w - m);
    #pragma unroll
    for (int off = 32; off > 0; off >>= 1) s += __shfl_xor(s, off);
    if (lane == 0) reds[wave] = s;
    __syncthreads();
    s = reds[0] + reds[1] + reds[2] + reds[3];
    float lse = m + __logf(s);
    v.x -= lse; v.y -= lse; v.z -= lse; v.w -= lse;
    ((float4*)p)[tid] = v;
}

extern "C" void kernel_launch(void* const* d_in, const int* in_sizes, int n_in,
                              void* d_out, int out_size, void* d_ws, size_t ws_size,
                              hipStream_t stream) {
    const float* x    = (const float*)d_in[0];
    const float* W_fc = (const float*)d_in[1];
    const float* b_fc = (const float*)d_in[2];
    const float* W_q  = (const float*)d_in[3];
    float* out = (float*)d_out;

    char* ws = (char*)d_ws;
    unsigned short* xb   = (unsigned short*)(ws);                        // 32 MiB
    unsigned short* wfcb = (unsigned short*)(ws + 33554432);             // 2 MiB
    unsigned short* wqb  = (unsigned short*)(ws + 35651584);             // 1 MiB
    float*          wqsq = (float*)(ws + 36700160);                      // 4 KiB
    unsigned short* hb   = (unsigned short*)(ws + 36704256);             // 8 MiB
    float*          hsq  = (float*)(ws + 45092864);                      // 32 KiB

    cast_x_kernel<<<(B_ROWS * NX) / (256 * 8), 256, 0, stream>>>(x, xb);
    cast_wfc_kernel<<<(NH * NX) / (256 * 4), 256, 0, stream>>>(W_fc, wfcb);
    prep_wq_kernel<<<NY / 4, 256, 0, stream>>>(W_q, wqb, wqsq);
    gemm1_kernel<<<dim3(NH / 128, B_ROWS / 64), 256, 0, stream>>>(xb, wfcb, b_fc, hb);
    hsq_kernel<<<B_ROWS / 4, 256, 0, stream>>>(hb, hsq);
    gemm2_kernel<<<dim3(NY / 128, B_ROWS / 128), 256, 0, stream>>>(hb, wqb, hsq, wqsq, out);
    lse_kernel<<<B_ROWS, 256, 0, stream>>>(out);
}

// Round 3
// 179.343 us; speedup vs baseline: 1.1316x; 1.0203x over previous
//
#include <hip/hip_runtime.h>
#include <stdint.h>
#include <stddef.h>

#define B_ROWS 8192
#define NX 2048
#define NH 512
#define NY 1024

// prep kernel block split: elementwise cast blocks, then wq blocks
#define X_ELEMS (B_ROWS * NX)                 // 16777216 (relu+cast)
#define EW_ELEMS (X_ELEMS + NH * NX)          // + 1048576 (plain cast)
#define EW_BLOCKS (EW_ELEMS / (8 * 256))      // 8704
#define WQ_BLOCKS (NY / 4)                    // 256

typedef __attribute__((ext_vector_type(8))) short bf16x8;
typedef __attribute__((ext_vector_type(4))) short bf16x4;
typedef __attribute__((ext_vector_type(4))) float f32x4;

static __device__ __forceinline__ unsigned short f2bf(float f) {
    union { float f; unsigned int u; } c; c.f = f;
    unsigned int r = 0x7FFFu + ((c.u >> 16) & 1u);
    return (unsigned short)((c.u + r) >> 16);
}

static __device__ __forceinline__ void glld16(const void* g, void* l) {
    __builtin_amdgcn_global_load_lds(
        (const __attribute__((address_space(1))) unsigned int*)g,
        (__attribute__((address_space(3))) unsigned int*)l, 16, 0, 0);
}

// ---------------- prep: relu(x)->bf16, W_fc->bf16, W_q->bf16+rowsq, hsq=0 ----------------
__global__ __launch_bounds__(256) void prep_kernel(const float* __restrict__ x,
                                                   const float* __restrict__ wfc,
                                                   const float* __restrict__ wq,
                                                   unsigned short* __restrict__ xb,
                                                   unsigned short* __restrict__ wfcb,
                                                   unsigned short* __restrict__ wqb,
                                                   float* __restrict__ wqsq,
                                                   float* __restrict__ hsq) {
    const int bid = blockIdx.x;
    const int tid = threadIdx.x;
    if (bid < EW_BLOCKS) {
        size_t idx = ((size_t)bid * 256 + tid) * 8;
        if (idx < (size_t)X_ELEMS) {
            float4 a = *(const float4*)&x[idx];
            float4 b = *(const float4*)&x[idx + 4];
            bf16x8 o;
            o[0] = (short)f2bf(fmaxf(a.x, 0.f)); o[1] = (short)f2bf(fmaxf(a.y, 0.f));
            o[2] = (short)f2bf(fmaxf(a.z, 0.f)); o[3] = (short)f2bf(fmaxf(a.w, 0.f));
            o[4] = (short)f2bf(fmaxf(b.x, 0.f)); o[5] = (short)f2bf(fmaxf(b.y, 0.f));
            o[6] = (short)f2bf(fmaxf(b.z, 0.f)); o[7] = (short)f2bf(fmaxf(b.w, 0.f));
            *(bf16x8*)&xb[idx] = o;
        } else {
            size_t off = idx - X_ELEMS;
            float4 a = *(const float4*)&wfc[off];
            float4 b = *(const float4*)&wfc[off + 4];
            bf16x8 o;
            o[0] = (short)f2bf(a.x); o[1] = (short)f2bf(a.y);
            o[2] = (short)f2bf(a.z); o[3] = (short)f2bf(a.w);
            o[4] = (short)f2bf(b.x); o[5] = (short)f2bf(b.y);
            o[6] = (short)f2bf(b.z); o[7] = (short)f2bf(b.w);
            *(bf16x8*)&wfcb[off] = o;
        }
    } else {
        const int b2 = bid - EW_BLOCKS;        // 0..255
        const int lane = tid & 63;
        const int row = b2 * 4 + (tid >> 6);
        const float* p = wq + (size_t)row * NH + lane * 8;
        float4 a = *(const float4*)p;
        float4 b = *(const float4*)(p + 4);
        bf16x8 o;
        o[0] = (short)f2bf(a.x); o[1] = (short)f2bf(a.y);
        o[2] = (short)f2bf(a.z); o[3] = (short)f2bf(a.w);
        o[4] = (short)f2bf(b.x); o[5] = (short)f2bf(b.y);
        o[6] = (short)f2bf(b.z); o[7] = (short)f2bf(b.w);
        *(bf16x8*)&wqb[(size_t)row * NH + lane * 8] = o;
        float s = a.x*a.x + a.y*a.y + a.z*a.z + a.w*a.w
                + b.x*b.x + b.y*b.y + b.z*b.z + b.w*b.w;
        #pragma unroll
        for (int off = 32; off > 0; off >>= 1) s += __shfl_xor(s, off);
        if (lane == 0) wqsq[row] = s;
        if (tid < 32) hsq[b2 * 32 + tid] = 0.0f;   // zero-init for gemm1 atomics
    }
}

// ---------------- GEMM1: h = relu(xb @ wfcb^T + b) -> bf16, fused ||h||^2 ----------------
// tile 64(M) x 128(N), BK=128 as two swizzled 64-halves, 4 waves 2x2,
// wave tile 32x64, acc 2x4. hsq accumulated via quad-shuffle + atomicAdd.
__global__ __launch_bounds__(256, 3) void gemm1_kernel(const unsigned short* __restrict__ xb,
                                                       const unsigned short* __restrict__ wfcb,
                                                       const float* __restrict__ b_fc,
                                                       unsigned short* __restrict__ hb,
                                                       float* __restrict__ hsq) {
    __shared__ unsigned short As[2 * 64 * 64];    // two 8 KiB halves
    __shared__ unsigned short Bs[2 * 128 * 64];   // two 16 KiB halves

    const int tid = threadIdx.x;
    const int lane = tid & 63;
    const int wave = tid >> 6;
    const int wm = wave >> 1, wn = wave & 1;
    const int quad = lane >> 4;
    const int r = lane & 15;
    const int m0 = blockIdx.y * 64;
    const int n0 = blockIdx.x * 128;

    f32x4 acc[2][4];
    #pragma unroll
    for (int i = 0; i < 2; ++i)
        #pragma unroll
        for (int j = 0; j < 4; ++j) acc[i][j] = (f32x4)(0.0f);

    const int lrow = lane >> 3;
    const int gch = (lane & 7) ^ lrow;
    const char* xbB = (const char*)xb;
    const char* wfB = (const char*)wfcb;
    char* AsB = (char*)As;
    char* BsB = (char*)Bs;

    const int xk = r & 7;
    const int ch0 = ((quad) ^ xk) * 16;
    const int ch1 = ((4 + quad) ^ xk) * 16;
    const char* ardp = AsB + (wm * 32 + r) * 128;
    const char* brdp = BsB + (wn * 64 + r) * 128;

    for (int k0 = 0; k0 < NX; k0 += 128) {
        __syncthreads();
        #pragma unroll
        for (int t = 0; t < 2; ++t) {
            const int kk = (k0 + t * 64) * 2;
            #pragma unroll
            for (int c = 0; c < 2; ++c) {
                int R0 = wave * 16 + c * 8;
                glld16(xbB + (size_t)(m0 + R0 + lrow) * (NX * 2) + kk + gch * 16,
                       AsB + t * 8192 + R0 * 128);
            }
            #pragma unroll
            for (int c = 0; c < 4; ++c) {
                int R0 = wave * 32 + c * 8;
                glld16(wfB + (size_t)(n0 + R0 + lrow) * (NX * 2) + kk + gch * 16,
                       BsB + t * 16384 + R0 * 128);
            }
        }
        __syncthreads();

        #pragma unroll
        for (int t = 0; t < 2; ++t) {
            #pragma unroll
            for (int s = 0; s < 2; ++s) {
                const int ch = (s ? ch1 : ch0) + t * 0;
                const char* ap = ardp + t * 8192;
                const char* bp = brdp + t * 16384;
                bf16x8 af[2], bfv[4];
                #pragma unroll
                for (int i = 0; i < 2; ++i) af[i] = *(const bf16x8*)(ap + i * 16 * 128 + ch);
                #pragma unroll
                for (int j = 0; j < 4; ++j) bfv[j] = *(const bf16x8*)(bp + j * 16 * 128 + ch);
                #pragma unroll
                for (int i = 0; i < 2; ++i)
                    #pragma unroll
                    for (int j = 0; j < 4; ++j)
                        acc[i][j] = __builtin_amdgcn_mfma_f32_16x16x32_bf16(af[i], bfv[j], acc[i][j], 0, 0, 0);
            }
        }
    }

    float p[2][4];
    #pragma unroll
    for (int i = 0; i < 2; ++i)
        #pragma unroll
        for (int rr = 0; rr < 4; ++rr) p[i][rr] = 0.0f;

    #pragma unroll
    for (int i = 0; i < 2; ++i) {
        #pragma unroll
        for (int j = 0; j < 4; ++j) {
            int col = n0 + wn * 64 + j * 16 + r;
            float bias = b_fc[col];
            #pragma unroll
            for (int rr = 0; rr < 4; ++rr) {
                int row = m0 + wm * 32 + i * 16 + quad * 4 + rr;
                float v = fmaxf(acc[i][j][rr] + bias, 0.0f);
                hb[(size_t)row * NH + col] = f2bf(v);
                p[i][rr] += v * v;
            }
        }
    }
    // reduce p over the 16 lanes (r) of each quad, then atomic per row
    #pragma unroll
    for (int mask = 1; mask < 16; mask <<= 1) {
        #pragma unroll
        for (int i = 0; i < 2; ++i)
            #pragma unroll
            for (int rr = 0; rr < 4; ++rr)
                p[i][rr] += __shfl_xor(p[i][rr], mask);
    }
    if (r == 0) {
        #pragma unroll
        for (int i = 0; i < 2; ++i)
            #pragma unroll
            for (int rr = 0; rr < 4; ++rr)
                atomicAdd(&hsq[m0 + wm * 32 + i * 16 + quad * 4 + rr], p[i][rr]);
    }
}

// ---------------- GEMM2 + distance + t ----------------
// tile 128x128, BK=128 as two 64-halves, 4 waves 2x2, wave tile 64x64, acc 4x4.
// Only 4 K-iterations (NH=512).
__global__ __launch_bounds__(256, 2) void gemm2_kernel(const unsigned short* __restrict__ hb,
                                                       const unsigned short* __restrict__ wqb,
                                                       const float* __restrict__ hsq,
                                                       const float* __restrict__ wqsq,
                                                       float* __restrict__ out) {
    __shared__ unsigned short As[2 * 128 * 64];   // two 16 KiB halves
    __shared__ unsigned short Bs[2 * 128 * 64];   // two 16 KiB halves

    const int tid = threadIdx.x;
    const int lane = tid & 63;
    const int wave = tid >> 6;
    const int wm = wave >> 1, wn = wave & 1;
    const int quad = lane >> 4;
    const int r = lane & 15;
    const int m0 = blockIdx.y * 128;
    const int n0 = blockIdx.x * 128;

    f32x4 acc[4][4];
    #pragma unroll
    for (int i = 0; i < 4; ++i)
        #pragma unroll
        for (int j = 0; j < 4; ++j) acc[i][j] = (f32x4)(0.0f);

    const int lrow = lane >> 3;
    const int gch = (lane & 7) ^ lrow;
    const char* hbB = (const char*)hb;
    const char* wqB = (const char*)wqb;
    char* AsB = (char*)As;
    char* BsB = (char*)Bs;

    const int xk = r & 7;
    const int ch0 = ((quad) ^ xk) * 16;
    const int ch1 = ((4 + quad) ^ xk) * 16;
    const char* ardp = AsB + (wm * 64 + r) * 128;
    const char* brdp = BsB + (wn * 64 + r) * 128;

    for (int k0 = 0; k0 < NH; k0 += 128) {
        __syncthreads();
        #pragma unroll
        for (int t = 0; t < 2; ++t) {
            const int kk = (k0 + t * 64) * 2;
            #pragma unroll
            for (int c = 0; c < 4; ++c) {
                int R0 = wave * 32 + c * 8;
                glld16(hbB + (size_t)(m0 + R0 + lrow) * (NH * 2) + kk + gch * 16,
                       AsB + t * 16384 + R0 * 128);
                glld16(wqB + (size_t)(n0 + R0 + lrow) * (NH * 2) + kk + gch * 16,
                       BsB + t * 16384 + R0 * 128);
            }
        }
        __syncthreads();

        #pragma unroll
        for (int t = 0; t < 2; ++t) {
            #pragma unroll
            for (int s = 0; s < 2; ++s) {
                const int ch = s ? ch1 : ch0;
                const char* ap = ardp + t * 16384;
                const char* bp = brdp + t * 16384;
                bf16x8 af[4], bfv[4];
                #pragma unroll
                for (int i = 0; i < 4; ++i) af[i] = *(const bf16x8*)(ap + i * 16 * 128 + ch);
                #pragma unroll
                for (int j = 0; j < 4; ++j) bfv[j] = *(const bf16x8*)(bp + j * 16 * 128 + ch);
                #pragma unroll
                for (int i = 0; i < 4; ++i)
                    #pragma unroll
                    for (int j = 0; j < 4; ++j)
                        acc[i][j] = __builtin_amdgcn_mfma_f32_16x16x32_bf16(af[i], bfv[j], acc[i][j], 0, 0, 0);
            }
        }
    }

    float hs[4][4];
    #pragma unroll
    for (int i = 0; i < 4; ++i)
        #pragma unroll
        for (int rr = 0; rr < 4; ++rr)
            hs[i][rr] = hsq[m0 + wm * 64 + i * 16 + quad * 4 + rr];

    #pragma unroll
    for (int i = 0; i < 4; ++i) {
        #pragma unroll
        for (int j = 0; j < 4; ++j) {
            int col = n0 + wn * 64 + j * 16 + r;
            float wq = wqsq[col];
            #pragma unroll
            for (int rr = 0; rr < 4; ++rr) {
                int row = m0 + wm * 64 + i * 16 + quad * 4 + rr;
                float d = hs[i][rr] - 2.0f * acc[i][j][rr] + wq;
                d = fmaxf(d, 0.0f);
                out[(size_t)row * NY + col] = -__logf(1.0f + d);
            }
        }
    }
}

// ---------------- per-row logsumexp (no max pass: t <= 0 so exp is safe) ----------------
__global__ __launch_bounds__(256) void lse_kernel(float* __restrict__ out) {
    __shared__ float reds[4];
    const int tid = threadIdx.x;
    const int lane = tid & 63;
    const int wave = tid >> 6;
    float* p = out + (size_t)blockIdx.x * NY;
    float4 v = ((const float4*)p)[tid];
    float s = __expf(v.x) + __expf(v.y) + __expf(v.z) + __expf(v.w);
    #pragma unroll
    for (int off = 32; off > 0; off >>= 1) s += __shfl_xor(s, off);
    if (lane == 0) reds[wave] = s;
    __syncthreads();
    float lse = __logf(reds[0] + reds[1] + reds[2] + reds[3]);
    v.x -= lse; v.y -= lse; v.z -= lse; v.w -= lse;
    ((float4*)p)[tid] = v;
}

extern "C" void kernel_launch(void* const* d_in, const int* in_sizes, int n_in,
                              void* d_out, int out_size, void* d_ws, size_t ws_size,
                              hipStream_t stream) {
    const float* x    = (const float*)d_in[0];
    const float* W_fc = (const float*)d_in[1];
    const float* b_fc = (const float*)d_in[2];
    const float* W_q  = (const float*)d_in[3];
    float* out = (float*)d_out;

    char* ws = (char*)d_ws;
    unsigned short* xb   = (unsigned short*)(ws);                        // 32 MiB
    unsigned short* wfcb = (unsigned short*)(ws + 33554432);             // 2 MiB
    unsigned short* wqb  = (unsigned short*)(ws + 35651584);             // 1 MiB
    float*          wqsq = (float*)(ws + 36700160);                      // 4 KiB
    unsigned short* hb   = (unsigned short*)(ws + 36704256);             // 8 MiB
    float*          hsq  = (float*)(ws + 45092864);                      // 32 KiB

    prep_kernel<<<EW_BLOCKS + WQ_BLOCKS, 256, 0, stream>>>(x, W_fc, W_q, xb, wfcb, wqb, wqsq, hsq);
    gemm1_kernel<<<dim3(NH / 128, B_ROWS / 64), 256, 0, stream>>>(xb, wfcb, b_fc, hb, hsq);
    gemm2_kernel<<<dim3(NY / 128, B_ROWS / 128), 256, 0, stream>>>(hb, wqb, hsq, wqsq, out);
    lse_kernel<<<B_ROWS, 256, 0, stream>>>(out);
}